// Round 14
// baseline (234.443 us; speedup 1.0000x reference)
//
#include <hip/hip_runtime.h>
#include <hip/hip_bf16.h>
#include <stdint.h>

#define BQ   8
#define SEQ  2048
#define EMB  512
#define KVB  32
#define QTILE 128

typedef __attribute__((ext_vector_type(8))) short short8;
typedef __attribute__((ext_vector_type(4))) float floatx4;
typedef __attribute__((ext_vector_type(4))) unsigned short ushort4_t;
typedef __hip_bfloat16 bf16;

__device__ __forceinline__ unsigned short f2bf(float f) {
    union { bf16 h; unsigned short u; } c;
    c.h = __float2bfloat16(f);
    return c.u;
}
__device__ __forceinline__ float exp2_fast(float x) {
    float r;
    asm("v_exp_f32 %0, %1" : "=v"(r) : "v"(x));
    return r;
}

// ---------------- prep: cvt X, cvt W (scaled), mask->bias -----------------
// grid.x = 8192 (X) + 768 (W) + 16 (mask) = 8976
// Base-2 softmax: log2e folded into qscale and bias constants.
__global__ __launch_bounds__(256) void prep(
    const float* __restrict__ feat,
    const float* __restrict__ Wq, const float* __restrict__ Wk,
    const float* __restrict__ Wv, const void* __restrict__ mraw,
    bf16* __restrict__ Xb, bf16* __restrict__ Wqb, bf16* __restrict__ Wkb,
    bf16* __restrict__ Wvb, float* __restrict__ bias, float qscale)
{
    __shared__ int bad;
    const int bx = blockIdx.x;
    const int tid = threadIdx.x;
    if (bx < 8192) {                        // X
        long i = (long)bx * 256 + tid;
        floatx4 v = ((const floatx4*)feat)[i];
        ushort4_t o;
        o.x = f2bf(v.x); o.y = f2bf(v.y); o.z = f2bf(v.z); o.w = f2bf(v.w);
        ((ushort4_t*)Xb)[i] = o;
    } else if (bx < 8960) {                 // W: 3 x 256 blocks
        int w = (bx - 8192) >> 8;
        int blk = (bx - 8192) & 255;
        const float* in = (w == 0) ? Wq : (w == 1) ? Wk : Wv;
        bf16* out = (w == 0) ? Wqb : (w == 1) ? Wkb : Wvb;
        float scale = (w == 0) ? qscale : 1.0f;
        long i = (long)blk * 256 + tid;
        floatx4 v = ((const floatx4*)in)[i];
        ushort4_t o;
        o.x = f2bf(v.x * scale); o.y = f2bf(v.y * scale);
        o.z = f2bf(v.z * scale); o.w = f2bf(v.w * scale);
        ((ushort4_t*)out)[i] = o;
    } else {                                // mask: 16 blocks
        if (tid == 0) bad = 0;
        __syncthreads();
        const int* mi = (const int*)mraw;
        int local = 0;
        for (int i = tid; i < 4096; i += 256) {
            unsigned v = (unsigned)mi[i];
            if (v > 1u) local = 1;
        }
        if (local) atomicOr(&bad, 1);
        __syncthreads();
        bool as_int = (bad == 0);
        const unsigned char* mb = (const unsigned char*)mraw;
        const int start = (bx - 8960) * (BQ * SEQ / 16);
        for (int i = start + tid; i < start + BQ * SEQ / 16; i += 256) {
            int mv = as_int ? mi[i] : (int)mb[i];
            // static base -12 in e-units -> -12*log2e in base-2 units
            bias[i] = mv ? -1e9f : -17.312340490667560f;
        }
    }
}

// ---------------- fused QKV projection, BK=64 (R9-verified) ---------------
__global__ __launch_bounds__(256) void gemm_qkv(
    const bf16* __restrict__ X,
    const bf16* __restrict__ Wqb, const bf16* __restrict__ Wkb,
    const bf16* __restrict__ Wvb,
    bf16* __restrict__ Qd, bf16* __restrict__ Kd, bf16* __restrict__ Vtp)
{
    __shared__ __attribute__((aligned(16))) bf16 lA[128 * 64];
    __shared__ __attribute__((aligned(16))) bf16 lB[128 * 64];

    const int which = blockIdx.x >> 2;
    const bf16* Bt = (which == 0) ? Wqb : (which == 1) ? Wkb : Wvb;

    const int tid  = threadIdx.x;
    const int lane = tid & 63;
    const int wv   = tid >> 6;
    const int wr   = wv >> 1, wc = wv & 1;
    const long brow = (long)blockIdx.y * 128;
    const long bcol = (long)(blockIdx.x & 3) * 128;

    floatx4 acc[4][4];
#pragma unroll
    for (int m = 0; m < 4; m++)
#pragma unroll
        for (int n = 0; n < 4; n++) acc[m][n] = (floatx4)0.0f;

    const int hi  = lane >> 4;
    const int r16 = lane & 15;

    for (int kt = 0; kt < EMB; kt += 64) {
#pragma unroll
        for (int i = 0; i < 4; ++i) {
            int c = i * 256 + tid;
            int row = c >> 3, cc = c & 7;
            const bf16* src = X + (brow + row) * (long)EMB + kt + ((cc ^ (row & 7)) << 3);
            __builtin_amdgcn_global_load_lds(
                (const __attribute__((address_space(1))) void*)src,
                (__attribute__((address_space(3))) void*)(&lA[c * 8]),
                16, 0, 0);
        }
#pragma unroll
        for (int i = 0; i < 4; ++i) {
            int c = i * 256 + tid;
            int row = c >> 3, cc = c & 7;
            const bf16* src = Bt + (bcol + row) * (long)EMB + kt + ((cc ^ (row & 7)) << 3);
            __builtin_amdgcn_global_load_lds(
                (const __attribute__((address_space(1))) void*)src,
                (__attribute__((address_space(3))) void*)(&lB[c * 8]),
                16, 0, 0);
        }
        __syncthreads();

#pragma unroll
        for (int hh = 0; hh < 2; hh++) {
            short8 af[4], bfr[4];
#pragma unroll
            for (int m = 0; m < 4; m++) {
                int row = wr * 64 + m * 16 + r16;
                af[m] = *(const short8*)((const char*)lA + row * 128
                                         + (((hh * 4 + hi) ^ (row & 7)) << 4));
            }
#pragma unroll
            for (int n = 0; n < 4; n++) {
                int row = wc * 64 + n * 16 + r16;
                bfr[n] = *(const short8*)((const char*)lB + row * 128
                                          + (((hh * 4 + hi) ^ (row & 7)) << 4));
            }
#pragma unroll
            for (int m = 0; m < 4; m++)
#pragma unroll
                for (int n = 0; n < 4; n++)
                    acc[m][n] = __builtin_amdgcn_mfma_f32_16x16x32_bf16(
                        af[m], bfr[n], acc[m][n], 0, 0, 0);
        }
        __syncthreads();
    }

#pragma unroll
    for (int m = 0; m < 4; m++) {
#pragma unroll
        for (int n = 0; n < 4; n++) {
#pragma unroll
            for (int j = 0; j < 4; j++) {
                long row = brow + wr * 64 + m * 16 + hi * 4 + j;
                long col = bcol + wc * 64 + n * 16 + r16;
                float v = acc[m][n][j];
                if (which == 0) {
                    Qd[row * EMB + col] = __float2bfloat16(v);
                } else if (which == 1) {
                    Kd[row * EMB + col] = __float2bfloat16(v);
                } else {
                    // Vtp[b][e][key], keys pi-permuted per 32-block:
                    // pos = ((k>>2)&3)*8 + ((k>>4)&1)*4 + (k&3)
                    long bb = row >> 11;
                    int  t  = (int)(row & 2047);
                    int  t5 = t & 31;
                    int  tp = (t & ~31) | (((t5 >> 2) & 3) << 3)
                            | (((t5 >> 4) & 1) << 2) | (t5 & 3);
                    Vtp[(bb * EMB + col) * SEQ + tp] = __float2bfloat16(v);
                }
            }
        }
    }
}

// ---------------- fused flash attention (full-KV, in-kernel normalize) ----
// grid 128: bid&7=batch (XCD), bid>>3=qtile (128 rows). NT=64 tiles of 32.
// Wave w owns q-rows q0+w*16..+15 (all 512 e-cols). S^T = mfma(K,Q), 4
// independent MFMA chains. Static base-2 softmax: P = 2^(s'+b'); per-lane
// l partials, one reduce at epilogue; out = oacc / l written f32 directly.
// PV: pa=[p0,p1] bf16; B-frag = ONE b128 from key-permuted Vlds.
// K,V double-buffered LDS; 1 barrier/tile. V rotation (col>>1)&3.
__global__ __launch_bounds__(512) void flash_attn(
    const bf16* __restrict__ Q, const bf16* __restrict__ K,
    const bf16* __restrict__ Vtp, const float* __restrict__ bias,
    float* __restrict__ out)
{
    __shared__ __attribute__((aligned(16))) char smem[2 * 32768 + 2 * 32768 + SEQ * 4];
    bf16* Klds0 = (bf16*)smem;                         // [2][32*512]
    bf16* Vlds0 = (bf16*)(smem + 65536);               // [2][512*32] permuted keys
    float* biasLds = (float*)(smem + 131072);          // [2048]

    const int tid  = threadIdx.x;
    const int lane = tid & 63;
    const int wv   = tid >> 6;          // 0..7
    const int r16  = lane & 15, hi = lane >> 4;

    const int bid = blockIdx.x;
    const int b   = bid & 7;            // batch -> XCD
    const int qt  = bid >> 3;           // 0..15
    const long q0 = (long)qt * QTILE;
    const int NT  = SEQ / KVB;          // 64

    const bf16* Qb = Q   + (long)b * SEQ * EMB;
    const bf16* Kb = K   + (long)b * SEQ * EMB;
    const bf16* Vb = Vtp + (long)b * EMB * SEQ;
    const float* biasb = bias + (long)b * SEQ;

    ((floatx4*)biasLds)[tid] = ((const floatx4*)biasb)[tid];   // 512 x 16B = 8KB

    // ALL 16 Q fragments hoisted
    const bf16* qrow = Qb + (q0 + wv * 16 + r16) * EMB;
    short8 qf[16];
#pragma unroll
    for (int ks = 0; ks < 16; ks++)
        qf[ks] = *(const short8*)(qrow + ks * 32 + hi * 8);

    floatx4 oacc[32];
#pragma unroll
    for (int nf = 0; nf < 32; nf++) oacc[nf] = (floatx4)0.f;

    float l_r = 0.f;                    // per-lane partial; reduced at end

    auto stage = [&](int buf, int t) {
        bf16* kd = Klds0 + buf * (KVB * EMB);
        bf16* vd = Vlds0 + buf * (EMB * KVB);
#pragma unroll
        for (int i = 0; i < 4; i++) {
            int c = i * 512 + tid;          // K chunk id
            int row = c >> 6, cc = c & 63;
            const bf16* src = Kb + ((long)t * KVB + row) * EMB + ((cc ^ (row & 7)) << 3);
            __builtin_amdgcn_global_load_lds(
                (const __attribute__((address_space(1))) void*)src,
                (__attribute__((address_space(3))) void*)(kd + c * 8),
                16, 0, 0);
        }
#pragma unroll
        for (int i = 0; i < 4; i++) {
            int c = i * 512 + tid;          // V chunk id
            int col = c >> 2, ch = c & 3;
            const bf16* src = Vb + (long)col * SEQ + t * KVB
                            + ((ch ^ ((col >> 1) & 3)) << 3);
            __builtin_amdgcn_global_load_lds(
                (const __attribute__((address_space(1))) void*)src,
                (__attribute__((address_space(3))) void*)(vd + c * 8),
                16, 0, 0);
        }
    };

    stage(0, 0);
    __syncthreads();

    for (int t = 0; t < NT; t++) {
        const int cur = t & 1;
        if (t + 1 < NT) stage(cur ^ 1, t + 1);

        // ---- S^T = mfma(A=K, B=Q): 4 independent chains ----
        floatx4 c0a = (floatx4)0.f, c0b = (floatx4)0.f;
        floatx4 c1a = (floatx4)0.f, c1b = (floatx4)0.f;
        const char* kbase = (const char*)(Klds0 + cur * (KVB * EMB));
        const int rowb0 = r16 * 1024, rowb1 = rowb0 + 16 * 1024;
        const int sw = r16 & 7;
        __builtin_amdgcn_s_setprio(1);
#pragma unroll
        for (int ks = 0; ks < 16; ks += 2) {
            const int cc0 = ((ks * 4 + hi) ^ sw) << 4;
            short8 k00 = *(const short8*)(kbase + rowb0 + cc0);
            c0a = __builtin_amdgcn_mfma_f32_16x16x32_bf16(k00, qf[ks], c0a, 0, 0, 0);
            short8 k10 = *(const short8*)(kbase + rowb1 + cc0);
            c1a = __builtin_amdgcn_mfma_f32_16x16x32_bf16(k10, qf[ks], c1a, 0, 0, 0);
            const int cc1 = (((ks + 1) * 4 + hi) ^ sw) << 4;
            short8 k01 = *(const short8*)(kbase + rowb0 + cc1);
            c0b = __builtin_amdgcn_mfma_f32_16x16x32_bf16(k01, qf[ks + 1], c0b, 0, 0, 0);
            short8 k11 = *(const short8*)(kbase + rowb1 + cc1);
            c1b = __builtin_amdgcn_mfma_f32_16x16x32_bf16(k11, qf[ks + 1], c1b, 0, 0, 0);
        }
        __builtin_amdgcn_s_setprio(0);
        floatx4 c0 = c0a + c0b, c1 = c1a + c1b;

        // ---- static base-2 softmax: P = 2^(s' + b'), per-lane l partial --
        float p0[4], p1[4];
#pragma unroll
        for (int j = 0; j < 4; j++) {
            p0[j] = exp2_fast(c0[j] + biasLds[t * KVB + hi * 4 + j]);
            p1[j] = exp2_fast(c1[j] + biasLds[t * KVB + 16 + hi * 4 + j]);
            l_r += p0[j] + p1[j];
        }

        short8 pa;                                 // slots [p0, p1] match Vtp perm
#pragma unroll
        for (int j = 0; j < 4; j++) {
            pa[j]     = (short)f2bf(p0[j]);
            pa[4 + j] = (short)f2bf(p1[j]);
        }

        // ---- O += P @ V: B-frag = one b128 from permuted Vlds ----
        const char* vbase = (const char*)(Vlds0 + cur * (EMB * KVB));
        __builtin_amdgcn_s_setprio(1);
#pragma unroll
        for (int cf = 0; cf < 32; cf++) {
            const int col = cf * 16 + r16;
            short8 vf = *(const short8*)(vbase + col * 64 + ((hi ^ ((col >> 1) & 3)) << 4));
            oacc[cf] = __builtin_amdgcn_mfma_f32_16x16x32_bf16(pa, vf, oacc[cf], 0, 0, 0);
        }
        __builtin_amdgcn_s_setprio(0);

        __syncthreads();   // staged t+1 drained; buffers swappable
    }

    // ---- epilogue: row-sum reduce, normalize, write f32 out directly ----
    l_r += __shfl_xor(l_r, 16);        // lanes with r16=R now hold row R's sum
    l_r += __shfl_xor(l_r, 32);

    float* ob = out + ((long)b * SEQ + q0 + wv * 16) * EMB;
#pragma unroll
    for (int j = 0; j < 4; j++) {
        int rowl = hi * 4 + j;
        float inv = 1.0f / __shfl(l_r, rowl);      // source lane r16 = rowl
#pragma unroll
        for (int cf = 0; cf < 32; cf++)
            ob[(long)rowl * EMB + cf * 16 + r16] = oacc[cf][j] * inv;
    }
}

// --------------------------------------------------------------------------
extern "C" void kernel_launch(void* const* d_in, const int* in_sizes, int n_in,
                              void* d_out, int out_size, void* d_ws, size_t ws_size,
                              hipStream_t stream)
{
    const float* feat = (const float*)d_in[0];
    const void*  mask = d_in[1];
    const float* Wq   = (const float*)d_in[2];
    const float* Wk   = (const float*)d_in[3];
    const float* Wv   = (const float*)d_in[4];
    float* out = (float*)d_out;

    const long M  = (long)BQ * SEQ;
    const long NE = M * EMB;
    const long NW = (long)EMB * EMB;

    char* ws = (char*)d_ws;
    size_t off = 0;
    auto carve = [&](size_t bytes) -> void* {
        void* p = ws + off;
        off = (off + bytes + 4095) & ~(size_t)4095;
        return p;
    };
    bf16*   Xb   = (bf16*)carve(NE * 2);
    bf16*   Wqb  = (bf16*)carve(NW * 2);
    bf16*   Wkb  = (bf16*)carve(NW * 2);
    bf16*   Wvb  = (bf16*)carve(NW * 2);
    bf16*   Qb   = (bf16*)carve(NE * 2);
    bf16*   Kb   = (bf16*)carve(NE * 2);
    bf16*   Vtp  = (bf16*)carve(NE * 2);
    float*  bias = (float*)carve(M * 4);
    (void)ws_size; (void)in_sizes; (void)n_in; (void)out_size;

    // 512^-0.5 * log2(e) folded into Wq (base-2 softmax)
    const float qscale = 0.063758717254359f;

    prep<<<dim3(8976), dim3(256), 0, stream>>>(
        feat, Wq, Wk, Wv, mask, Xb, Wqb, Wkb, Wvb, bias, qscale);

    gemm_qkv<<<dim3(12, 128), dim3(256), 0, stream>>>(Xb, Wqb, Wkb, Wvb, Qb, Kb, Vtp);

    flash_attn<<<dim3(128), dim3(512), 0, stream>>>(Qb, Kb, Vtp, bias, out);
}

// Round 15
// 181.189 us; speedup vs baseline: 1.2939x; 1.2939x over previous
//
#include <hip/hip_runtime.h>
#include <hip/hip_bf16.h>
#include <stdint.h>

#define BQ   8
#define SEQ  2048
#define EMB  512
#define KVB  32
#define HALF 1024   // keys per split-KV block
#define QTILE 128

typedef __attribute__((ext_vector_type(8))) short short8;
typedef __attribute__((ext_vector_type(4))) float floatx4;
typedef __attribute__((ext_vector_type(4))) unsigned short ushort4_t;
typedef __hip_bfloat16 bf16;

__device__ __forceinline__ unsigned short f2bf(float f) {
    union { bf16 h; unsigned short u; } c;
    c.h = __float2bfloat16(f);
    return c.u;
}
__device__ __forceinline__ float bf2f(unsigned short u) {
    union { unsigned int i; float f; } c;
    c.i = ((unsigned int)u) << 16;
    return c.f;
}
__device__ __forceinline__ float exp2_fast(float x) {
    float r;
    asm("v_exp_f32 %0, %1" : "=v"(r) : "v"(x));
    return r;
}

// ---------------- prep: cvt X, cvt W (scaled), mask->bias -----------------
// grid.x = 8192 (X) + 768 (W) + 16 (mask) = 8976
// Base-2 softmax: log2e folded into qscale and bias constants.
__global__ __launch_bounds__(256) void prep(
    const float* __restrict__ feat,
    const float* __restrict__ Wq, const float* __restrict__ Wk,
    const float* __restrict__ Wv, const void* __restrict__ mraw,
    bf16* __restrict__ Xb, bf16* __restrict__ Wqb, bf16* __restrict__ Wkb,
    bf16* __restrict__ Wvb, float* __restrict__ bias, float qscale)
{
    __shared__ int bad;
    const int bx = blockIdx.x;
    const int tid = threadIdx.x;
    if (bx < 8192) {                        // X
        long i = (long)bx * 256 + tid;
        floatx4 v = ((const floatx4*)feat)[i];
        ushort4_t o;
        o.x = f2bf(v.x); o.y = f2bf(v.y); o.z = f2bf(v.z); o.w = f2bf(v.w);
        ((ushort4_t*)Xb)[i] = o;
    } else if (bx < 8960) {                 // W: 3 x 256 blocks
        int w = (bx - 8192) >> 8;
        int blk = (bx - 8192) & 255;
        const float* in = (w == 0) ? Wq : (w == 1) ? Wk : Wv;
        bf16* out = (w == 0) ? Wqb : (w == 1) ? Wkb : Wvb;
        float scale = (w == 0) ? qscale : 1.0f;
        long i = (long)blk * 256 + tid;
        floatx4 v = ((const floatx4*)in)[i];
        ushort4_t o;
        o.x = f2bf(v.x * scale); o.y = f2bf(v.y * scale);
        o.z = f2bf(v.z * scale); o.w = f2bf(v.w * scale);
        ((ushort4_t*)out)[i] = o;
    } else {                                // mask: 16 blocks
        if (tid == 0) bad = 0;
        __syncthreads();
        const int* mi = (const int*)mraw;
        int local = 0;
        for (int i = tid; i < 4096; i += 256) {
            unsigned v = (unsigned)mi[i];
            if (v > 1u) local = 1;
        }
        if (local) atomicOr(&bad, 1);
        __syncthreads();
        bool as_int = (bad == 0);
        const unsigned char* mb = (const unsigned char*)mraw;
        const int start = (bx - 8960) * (BQ * SEQ / 16);
        for (int i = start + tid; i < start + BQ * SEQ / 16; i += 256) {
            int mv = as_int ? mi[i] : (int)mb[i];
            // static base -12 in e-units -> -12*log2e in base-2 units
            bias[i] = mv ? -1e9f : -17.312340490667560f;
        }
    }
}

// ---------------- fused QKV projection, BK=64, XCD-chunked ----------------
// 1-D grid 1536, bijective XCD swizzle: xcd = bid&7 owns 16 consecutive
// A-row-panels x all 12 (which,bcol) -> per-XCD L2 set = A 2MB + B 1.5MB.
__global__ __launch_bounds__(256) void gemm_qkv(
    const bf16* __restrict__ X,
    const bf16* __restrict__ Wqb, const bf16* __restrict__ Wkb,
    const bf16* __restrict__ Wvb,
    bf16* __restrict__ Qd, bf16* __restrict__ Kd, bf16* __restrict__ Vtp)
{
    __shared__ __attribute__((aligned(16))) bf16 lA[128 * 64];
    __shared__ __attribute__((aligned(16))) bf16 lB[128 * 64];

    // XCD-chunk swizzle (nwg=1536, 1536%8==0 -> simple bijection)
    const int lin = blockIdx.x;
    const int nb  = (lin & 7) * 192 + (lin >> 3);
    const int ytile = nb / 12;          // A row-panel 0..127
    const int xsel  = nb % 12;
    const int which = xsel >> 2;
    const bf16* Bt = (which == 0) ? Wqb : (which == 1) ? Wkb : Wvb;

    const int tid  = threadIdx.x;
    const int lane = tid & 63;
    const int wv   = tid >> 6;
    const int wr   = wv >> 1, wc = wv & 1;
    const long brow = (long)ytile * 128;
    const long bcol = (long)(xsel & 3) * 128;

    floatx4 acc[4][4];
#pragma unroll
    for (int m = 0; m < 4; m++)
#pragma unroll
        for (int n = 0; n < 4; n++) acc[m][n] = (floatx4)0.0f;

    const int hi  = lane >> 4;
    const int r16 = lane & 15;

    for (int kt = 0; kt < EMB; kt += 64) {
#pragma unroll
        for (int i = 0; i < 4; ++i) {
            int c = i * 256 + tid;
            int row = c >> 3, cc = c & 7;
            const bf16* src = X + (brow + row) * (long)EMB + kt + ((cc ^ (row & 7)) << 3);
            __builtin_amdgcn_global_load_lds(
                (const __attribute__((address_space(1))) void*)src,
                (__attribute__((address_space(3))) void*)(&lA[c * 8]),
                16, 0, 0);
        }
#pragma unroll
        for (int i = 0; i < 4; ++i) {
            int c = i * 256 + tid;
            int row = c >> 3, cc = c & 7;
            const bf16* src = Bt + (bcol + row) * (long)EMB + kt + ((cc ^ (row & 7)) << 3);
            __builtin_amdgcn_global_load_lds(
                (const __attribute__((address_space(1))) void*)src,
                (__attribute__((address_space(3))) void*)(&lB[c * 8]),
                16, 0, 0);
        }
        __syncthreads();

#pragma unroll
        for (int hh = 0; hh < 2; hh++) {
            short8 af[4], bfr[4];
#pragma unroll
            for (int m = 0; m < 4; m++) {
                int row = wr * 64 + m * 16 + r16;
                af[m] = *(const short8*)((const char*)lA + row * 128
                                         + (((hh * 4 + hi) ^ (row & 7)) << 4));
            }
#pragma unroll
            for (int n = 0; n < 4; n++) {
                int row = wc * 64 + n * 16 + r16;
                bfr[n] = *(const short8*)((const char*)lB + row * 128
                                          + (((hh * 4 + hi) ^ (row & 7)) << 4));
            }
#pragma unroll
            for (int m = 0; m < 4; m++)
#pragma unroll
                for (int n = 0; n < 4; n++)
                    acc[m][n] = __builtin_amdgcn_mfma_f32_16x16x32_bf16(
                        af[m], bfr[n], acc[m][n], 0, 0, 0);
        }
        __syncthreads();
    }

#pragma unroll
    for (int m = 0; m < 4; m++) {
#pragma unroll
        for (int n = 0; n < 4; n++) {
#pragma unroll
            for (int j = 0; j < 4; j++) {
                long row = brow + wr * 64 + m * 16 + hi * 4 + j;
                long col = bcol + wc * 64 + n * 16 + r16;
                float v = acc[m][n][j];
                if (which == 0) {
                    Qd[row * EMB + col] = __float2bfloat16(v);
                } else if (which == 1) {
                    Kd[row * EMB + col] = __float2bfloat16(v);
                } else {
                    // Vtp[b][e][key], keys pi-permuted per 32-block:
                    // pos = ((k>>2)&3)*8 + ((k>>4)&1)*4 + (k&3)
                    long bb = row >> 11;
                    int  t  = (int)(row & 2047);
                    int  t5 = t & 31;
                    int  tp = (t & ~31) | (((t5 >> 2) & 3) << 3)
                            | (((t5 >> 4) & 1) << 2) | (t5 & 3);
                    Vtp[(bb * EMB + col) * SEQ + tp] = __float2bfloat16(v);
                }
            }
        }
    }
}

// ---------------- fused flash attention (R13-verified) --------------------
// grid 256: bid&7=batch (XCD), (bid>>3)&15=qtile(128 rows), bid>>7=KV half.
// Wave w owns q-rows q0+w*16..+15 (all 512 e-cols). S^T = mfma(K,Q), 4
// independent MFMA chains. Static base-2 softmax: P = 2^(s'+b'), no max
// tracking; per-lane l partials, single reduce at epilogue.
// PV: pa=[p0,p1] bf16; B-frag = ONE b128 from key-permuted Vlds.
// K,V double-buffered LDS; 1 barrier/tile. V rotation (col>>1)&3.
__global__ __launch_bounds__(512) void flash_attn(
    const bf16* __restrict__ Q, const bf16* __restrict__ K,
    const bf16* __restrict__ Vtp, const float* __restrict__ bias,
    bf16* __restrict__ part, float2* __restrict__ ml)
{
    __shared__ __attribute__((aligned(16))) char smem[2 * 32768 + 2 * 32768 + HALF * 4];
    bf16* Klds0 = (bf16*)smem;                         // [2][32*512]
    bf16* Vlds0 = (bf16*)(smem + 65536);               // [2][512*32] permuted keys
    float* biasLds = (float*)(smem + 131072);          // [1024]

    const int tid  = threadIdx.x;
    const int lane = tid & 63;
    const int wv   = tid >> 6;          // 0..7
    const int r16  = lane & 15, hi = lane >> 4;

    const int bid = blockIdx.x;
    const int b   = bid & 7;            // batch -> XCD
    const int qt  = (bid >> 3) & 15;    // 0..15
    const int h   = bid >> 7;           // KV half
    const long q0  = (long)qt * QTILE;
    const long kv0 = (long)h * HALF;
    const int NT   = HALF / KVB;        // 32

    const bf16* Qb = Q   + (long)b * SEQ * EMB;
    const bf16* Kb = K   + (long)b * SEQ * EMB + kv0 * EMB;
    const bf16* Vb = Vtp + (long)b * EMB * SEQ;
    const float* biasb = bias + (long)b * SEQ + kv0;

    if (tid < HALF / 4)
        *(floatx4*)&biasLds[tid * 4] = *(const floatx4*)&biasb[tid * 4];

    // ALL 16 Q fragments hoisted
    const bf16* qrow = Qb + (q0 + wv * 16 + r16) * EMB;
    short8 qf[16];
#pragma unroll
    for (int ks = 0; ks < 16; ks++)
        qf[ks] = *(const short8*)(qrow + ks * 32 + hi * 8);

    floatx4 oacc[32];
#pragma unroll
    for (int nf = 0; nf < 32; nf++) oacc[nf] = (floatx4)0.f;

    float l_r = 0.f;                    // per-lane partial; reduced at end

    auto stage = [&](int buf, int t) {
        bf16* kd = Klds0 + buf * (KVB * EMB);
        bf16* vd = Vlds0 + buf * (EMB * KVB);
#pragma unroll
        for (int i = 0; i < 4; i++) {
            int c = i * 512 + tid;          // K chunk id
            int row = c >> 6, cc = c & 63;
            const bf16* src = Kb + ((long)t * KVB + row) * EMB + ((cc ^ (row & 7)) << 3);
            __builtin_amdgcn_global_load_lds(
                (const __attribute__((address_space(1))) void*)src,
                (__attribute__((address_space(3))) void*)(kd + c * 8),
                16, 0, 0);
        }
#pragma unroll
        for (int i = 0; i < 4; i++) {
            int c = i * 512 + tid;          // V chunk id
            int col = c >> 2, ch = c & 3;
            const bf16* src = Vb + (long)col * SEQ + kv0 + t * KVB
                            + ((ch ^ ((col >> 1) & 3)) << 3);
            __builtin_amdgcn_global_load_lds(
                (const __attribute__((address_space(1))) void*)src,
                (__attribute__((address_space(3))) void*)(vd + c * 8),
                16, 0, 0);
        }
    };

    stage(0, 0);
    __syncthreads();

    for (int t = 0; t < NT; t++) {
        const int cur = t & 1;
        if (t + 1 < NT) stage(cur ^ 1, t + 1);

        // ---- S^T = mfma(A=K, B=Q): 4 independent chains ----
        floatx4 c0a = (floatx4)0.f, c0b = (floatx4)0.f;
        floatx4 c1a = (floatx4)0.f, c1b = (floatx4)0.f;
        const char* kbase = (const char*)(Klds0 + cur * (KVB * EMB));
        const int rowb0 = r16 * 1024, rowb1 = rowb0 + 16 * 1024;
        const int sw = r16 & 7;
        __builtin_amdgcn_s_setprio(1);
#pragma unroll
        for (int ks = 0; ks < 16; ks += 2) {
            const int cc0 = ((ks * 4 + hi) ^ sw) << 4;
            short8 k00 = *(const short8*)(kbase + rowb0 + cc0);
            c0a = __builtin_amdgcn_mfma_f32_16x16x32_bf16(k00, qf[ks], c0a, 0, 0, 0);
            short8 k10 = *(const short8*)(kbase + rowb1 + cc0);
            c1a = __builtin_amdgcn_mfma_f32_16x16x32_bf16(k10, qf[ks], c1a, 0, 0, 0);
            const int cc1 = (((ks + 1) * 4 + hi) ^ sw) << 4;
            short8 k01 = *(const short8*)(kbase + rowb0 + cc1);
            c0b = __builtin_amdgcn_mfma_f32_16x16x32_bf16(k01, qf[ks + 1], c0b, 0, 0, 0);
            short8 k11 = *(const short8*)(kbase + rowb1 + cc1);
            c1b = __builtin_amdgcn_mfma_f32_16x16x32_bf16(k11, qf[ks + 1], c1b, 0, 0, 0);
        }
        __builtin_amdgcn_s_setprio(0);
        floatx4 c0 = c0a + c0b, c1 = c1a + c1b;

        // ---- static base-2 softmax: P = 2^(s' + b'), per-lane l partial --
        float p0[4], p1[4];
#pragma unroll
        for (int j = 0; j < 4; j++) {
            p0[j] = exp2_fast(c0[j] + biasLds[t * KVB + hi * 4 + j]);
            p1[j] = exp2_fast(c1[j] + biasLds[t * KVB + 16 + hi * 4 + j]);
            l_r += p0[j] + p1[j];
        }

        short8 pa;                                 // slots [p0, p1] match Vtp perm
#pragma unroll
        for (int j = 0; j < 4; j++) {
            pa[j]     = (short)f2bf(p0[j]);
            pa[4 + j] = (short)f2bf(p1[j]);
        }

        // ---- O += P @ V: B-frag = one b128 from permuted Vlds ----
        const char* vbase = (const char*)(Vlds0 + cur * (EMB * KVB));
        __builtin_amdgcn_s_setprio(1);
#pragma unroll
        for (int cf = 0; cf < 32; cf++) {
            const int col = cf * 16 + r16;
            short8 vf = *(const short8*)(vbase + col * 64 + ((hi ^ ((col >> 1) & 3)) << 4));
            oacc[cf] = __builtin_amdgcn_mfma_f32_16x16x32_bf16(pa, vf, oacc[cf], 0, 0, 0);
        }
        __builtin_amdgcn_s_setprio(0);

        __syncthreads();   // staged t+1 drained; buffers swappable
    }

    // ---- epilogue: unnormalized bf16 O partial + (m=12, l) per q-row ----
    bf16* pb = part + (long)bid * QTILE * EMB;
#pragma unroll
    for (int j = 0; j < 4; j++) {
        long row = wv * 16 + hi * 4 + j;
#pragma unroll
        for (int cf = 0; cf < 32; cf++)
            pb[row * EMB + cf * 16 + r16] = __float2bfloat16(oacc[cf][j]);
    }
    l_r += __shfl_xor(l_r, 16);        // deferred row-sum reduce (once)
    l_r += __shfl_xor(l_r, 32);
    if (hi == 0)
        ml[(long)bid * QTILE + wv * 16 + r16] = make_float2(12.0f, l_r);
}

// ---------------- combine the two KV halves (bf16 partials) ---------------
__global__ __launch_bounds__(128) void combine_halves(
    const bf16* __restrict__ part, const float2* __restrict__ ml,
    float* __restrict__ out)
{
    const int r  = blockIdx.x;              // 0..16383 global q-row
    const int b  = r >> 11;
    const int rb = r & 2047;
    const int qt = rb >> 7;
    const int rr = rb & 127;
    const int s0 = qt * 8 + b;              // slot of half 0
    const int s1 = s0 + 128;

    float2 ml0 = ml[(long)s0 * QTILE + rr];
    float2 ml1 = ml[(long)s1 * QTILE + rr];
    float M  = fmaxf(ml0.x, ml1.x);
    float w0 = __expf(ml0.x - M), w1 = __expf(ml1.x - M);
    float inv = 1.0f / (w0 * ml0.y + w1 * ml1.y);
    w0 *= inv; w1 *= inv;

    const ushort4_t* p0 = (const ushort4_t*)((const unsigned short*)part
                          + ((long)s0 * QTILE + rr) * EMB);
    const ushort4_t* p1 = (const ushort4_t*)((const unsigned short*)part
                          + ((long)s1 * QTILE + rr) * EMB);
    floatx4* po = (floatx4*)(out + (long)r * EMB);
    int c = threadIdx.x;                    // 128 threads x 4 = 512
    ushort4_t a = p0[c], d = p1[c];
    floatx4 o;
    o.x = bf2f(a.x) * w0 + bf2f(d.x) * w1;
    o.y = bf2f(a.y) * w0 + bf2f(d.y) * w1;
    o.z = bf2f(a.z) * w0 + bf2f(d.z) * w1;
    o.w = bf2f(a.w) * w0 + bf2f(d.w) * w1;
    po[c] = o;
}

// --------------------------------------------------------------------------
extern "C" void kernel_launch(void* const* d_in, const int* in_sizes, int n_in,
                              void* d_out, int out_size, void* d_ws, size_t ws_size,
                              hipStream_t stream)
{
    const float* feat = (const float*)d_in[0];
    const void*  mask = d_in[1];
    const float* Wq   = (const float*)d_in[2];
    const float* Wk   = (const float*)d_in[3];
    const float* Wv   = (const float*)d_in[4];
    float* out = (float*)d_out;

    const long M  = (long)BQ * SEQ;
    const long NE = M * EMB;
    const long NW = (long)EMB * EMB;

    char* ws = (char*)d_ws;
    size_t off = 0;
    auto carve = [&](size_t bytes) -> void* {
        void* p = ws + off;
        off = (off + bytes + 4095) & ~(size_t)4095;
        return p;
    };
    bf16*   Xb   = (bf16*)carve(NE * 2);
    bf16*   Wqb  = (bf16*)carve(NW * 2);
    bf16*   Wkb  = (bf16*)carve(NW * 2);
    bf16*   Wvb  = (bf16*)carve(NW * 2);
    bf16*   Qb   = (bf16*)carve(NE * 2);
    bf16*   Kb   = (bf16*)carve(NE * 2);
    bf16*   Vtp  = (bf16*)carve(NE * 2);
    float*  bias = (float*)carve(M * 4);
    bf16*   part = (bf16*)carve((long)256 * QTILE * EMB * 2);   // 32MB
    float2* ml   = (float2*)carve((long)256 * QTILE * 8);
    (void)ws_size; (void)in_sizes; (void)n_in; (void)out_size;

    // 512^-0.5 * log2(e) folded into Wq (base-2 softmax)
    const float qscale = 0.063758717254359f;

    prep<<<dim3(8976), dim3(256), 0, stream>>>(
        feat, Wq, Wk, Wv, mask, Xb, Wqb, Wkb, Wvb, bias, qscale);

    gemm_qkv<<<dim3(1536), dim3(256), 0, stream>>>(Xb, Wqb, Wkb, Wvb, Qb, Kb, Vtp);

    flash_attn<<<dim3(256), dim3(512), 0, stream>>>(Qb, Kb, Vtp, bias, part, ml);
    combine_halves<<<dim3(BQ * SEQ), dim3(128), 0, stream>>>(part, ml, out);
}